// Round 3
// baseline (15251.952 us; speedup 1.0000x reference)
//
#include <hip/hip_runtime.h>
#include <math.h>

#define NBLK 256
#define NTHR 256

namespace spinn {

constexpr int Bb = 64;     // batch
constexpr int Ss = 48;     // seq len
constexpr int Hh = 256;    // hidden
constexpr int TT = 96;     // time = 2*S
constexpr int Mm = 193;    // stack rows = 1 + 2*time
constexpr int H3 = 768;    // 3H
constexpr int MLPD = 1024;

__device__ __forceinline__ float sigf(float x) { return 1.0f / (1.0f + expf(-x)); }

// Inline-asm global atomic add with return (sc0). Avoids the gfx950 backend
// bug where flat-pointer atomicrmw expansion emits an illegal
// V_CMP_NE_U32 $src_shared_base (register-class error). global_atomic_add
// is the global-AS instruction directly; atomics are coherent at the
// device coherence point (works cross-XCD).
__device__ __forceinline__ unsigned gadd_ret(unsigned* p, unsigned v) {
    unsigned old;
    asm volatile("global_atomic_add %0, %1, %2, off sc0\n\t"
                 "s_waitcnt vmcnt(0)"
                 : "=v"(old)
                 : "v"(p), "v"(v)
                 : "memory");
    return old;
}

// ---- grid barrier: monotonic counter, inline-asm atomics ----
// target = barrier_number * NBLK; no reset, no ABA.
__device__ __forceinline__ void gbar(unsigned* cnt, unsigned target) {
    __syncthreads();
    if (threadIdx.x == 0) {
        __threadfence();  // release prior global writes
        (void)gadd_ret(cnt, 1u);
        while (gadd_ret(cnt, 0u) < target) {  // coherent RMW read
            __builtin_amdgcn_s_sleep(8);
        }
        __threadfence();  // acquire
    }
    __syncthreads();
}

// inclusive Hillis-Steele scan of 256 LDS slots (caller syncs after fill)
__device__ __forceinline__ void scan256(float* a, int tid) {
    for (int off = 1; off < 256; off <<= 1) {
        float v = (tid >= off) ? a[tid - off] : 0.0f;
        __syncthreads();
        a[tid] = a[tid] + v;
        __syncthreads();
    }
}

}  // namespace spinn

using namespace spinn;

__global__ void __launch_bounds__(NTHR, 1) spinn_kernel(
    const int* __restrict__ x, const float* __restrict__ emb,
    const float* __restrict__ wih, const float* __restrict__ whh,
    const float* __restrict__ bih, const float* __restrict__ bhh,
    const float* __restrict__ aw, const float* __restrict__ ab,
    const float* __restrict__ tlw, const float* __restrict__ tlb,
    const float* __restrict__ trw, const float* __restrict__ trb,
    const float* __restrict__ l0w, const float* __restrict__ l0b,
    const float* __restrict__ l1w, const float* __restrict__ l1b,
    const float* __restrict__ l2w, const float* __restrict__ l2b,
    float* __restrict__ out, float* __restrict__ wsf, unsigned* __restrict__ bar)
{
    const int tid = threadIdx.x;
    const int bid = blockIdx.x;
    unsigned* cnt = bar;
    unsigned barnum = 0;

    // ---- workspace layout (floats) ----
    float* Bemb = wsf;                          // [64][48][256]
    float* V    = Bemb + Bb * Ss * Hh;          // [193][64][256]
    float* Sbuf = V + (size_t)Mm * Bb * Hh;     // 2x [193][64]
    float* Hbuf = Sbuf + 2 * Mm * Bb;           // 2x [64][256]
    float* Cc   = Hbuf + 2 * Bb * Hh;           // [64][256]
    float* SBb  = Cc + Bb * Hh;                 // 2x [64][48]
    float* XT   = SBb + 2 * Bb * Ss;            // [64][768]
    float* R1   = XT + Bb * H3;                 // [64][256]
    float* R2   = R1 + Bb * Hh;                 // [64][256]
    float* Y0   = R2 + Bb * Hh;                 // [64][1024]
    float* Y1   = Y0 + Bb * MLPD;               // [64][1024]

    __shared__ float s_scan[256];
    __shared__ float s_w1[Mm + 7];
    __shared__ float s_w2[Mm + 7];
    __shared__ float s_wb[64];
    __shared__ float s_red[768];
    __shared__ float s_g[256];
    __shared__ float s_tg[320];
    __shared__ float s_ht[64];
    __shared__ float s_scan8[256 * 9];
    __shared__ float s_w1e[8 * 200];
    __shared__ float s_w2e[8 * 200];
    __shared__ float s_wbe[8 * 48];

    // ================= Phase I0: zero state, gather embeddings =================
    {
        // zero V, Sbuf(2), Hbuf(2), Cc  (contiguous region after Bemb)
        float4* z = reinterpret_cast<float4*>(V);
        const int nz4 = ((size_t)Mm * Bb * Hh + 2 * Mm * Bb + 2 * Bb * Hh + Bb * Hh) / 4;
        for (int i = bid * NTHR + tid; i < nz4; i += NBLK * NTHR)
            z[i] = make_float4(0.f, 0.f, 0.f, 0.f);
        // Bemb gather + initial s_b (parity 0)
        for (int rt = bid; rt < Bb * Ss; rt += NBLK) {
            int tok = x[rt];
            Bemb[(size_t)rt * Hh + tid] = emb[(size_t)tok * Hh + tid];
            if (tid == 0) SBb[rt] = (tok > 0) ? 1.0f : 0.0f;
        }
    }
    gbar(cnt, ++barnum * NBLK);

    // ================= Phase I1: initial xt (V=0 so x1=x2=0) =================
    {
        int e = bid >> 2, p = bid & 3;
        float sbval = (tid < Ss) ? SBb[e * Ss + tid] : 0.f;
        s_scan[tid] = sbval;
        __syncthreads();
        scan256(s_scan, tid);
        if (tid < Ss) {
            float P = s_scan[tid], Pm1 = tid ? s_scan[tid - 1] : 0.f;
            s_wb[tid] = fminf(P, 1.f) - fminf(Pm1, 1.f);
        }
        __syncthreads();
        int dl = tid & 63, ts = tid >> 6;
        int d = p * 64 + dl;
        float acb = 0.f;
        for (int t2 = ts * 12; t2 < ts * 12 + 12; t2++)
            acb += s_wb[t2] * Bemb[(e * Ss + t2) * Hh + d];
        s_red[tid] = acb;
        __syncthreads();
        if (ts == 0) {
            float xb = s_red[dl] + s_red[64 + dl] + s_red[128 + dl] + s_red[192 + dl];
            XT[e * H3 + d]       = xb;
            XT[e * H3 + 256 + d] = 0.f;
            XT[e * H3 + 512 + d] = 0.f;
        }
    }
    gbar(cnt, ++barnum * NBLK);

    // ================= time loop =================
    for (int t = 0; t < TT; t++) {
        const int par = t & 1;
        float* hcur  = Hbuf + par * Bb * Hh;
        float* hnxt  = Hbuf + (1 - par) * Bb * Hh;
        float* scur  = Sbuf + par * Mm * Bb;
        float* snxt  = Sbuf + (1 - par) * Mm * Bb;
        float* sbcur = SBb + par * Bb * Ss;
        float* sbnxt = SBb + (1 - par) * Bb * Ss;
        const int idx  = 191 - 2 * t;
        const int idx2 = 190 - 2 * t;

        // ---------- Phase L: LSTM gates ----------
        {
            int eg = bid >> 5, sl = bid & 31;
            int el = tid >> 5, rr = tid & 31;
            int e = eg * 8 + el;
            int q = rr >> 2, gate = rr & 3;
            int d = sl * 8 + q;
            int row = gate * Hh + d;
            float4 av = make_float4(0.f, 0.f, 0.f, 0.f);
            const float4* w4 = reinterpret_cast<const float4*>(wih + (size_t)row * H3);
            const float4* x4 = reinterpret_cast<const float4*>(XT + (size_t)e * H3);
            #pragma unroll 4
            for (int k = 0; k < H3 / 4; k++) {
                float4 a = w4[k], b = x4[k];
                av.x += a.x * b.x; av.y += a.y * b.y; av.z += a.z * b.z; av.w += a.w * b.w;
            }
            const float4* w42 = reinterpret_cast<const float4*>(whh + (size_t)row * Hh);
            const float4* h4  = reinterpret_cast<const float4*>(hcur + (size_t)e * Hh);
            #pragma unroll 4
            for (int k = 0; k < Hh / 4; k++) {
                float4 a = w42[k], b = h4[k];
                av.x += a.x * b.x; av.y += a.y * b.y; av.z += a.z * b.z; av.w += a.w * b.w;
            }
            float acc = bih[row] + bhh[row] + av.x + av.y + av.z + av.w;
            s_g[tid] = acc;
            __syncthreads();
            if (gate == 0) {
                float gi = s_g[tid], gf = s_g[tid + 1], gg = s_g[tid + 2], go = s_g[tid + 3];
                int ci = e * Hh + d;
                float c0 = Cc[ci];
                float cn = sigf(gf) * c0 + sigf(gi) * tanhf(gg);
                float hn = sigf(go) * tanhf(cn);
                Cc[ci] = cn;
                hnxt[ci] = hn;
            }
        }
        gbar(cnt, ++barnum * NBLK);

        // ---------- Phase T1: alphas, pop-read, s/sb update, buffer pop ----------
        {
            int e = bid >> 2, p = bid & 3;
            // alphas (redundant per block)
            float hv = hnxt[e * Hh + tid];
            s_red[tid]       = hv * aw[tid];
            s_red[256 + tid] = hv * aw[Hh + tid];
            __syncthreads();
            for (int off = 128; off >= 1; off >>= 1) {
                if (tid < off) {
                    s_red[tid] += s_red[tid + off];
                    s_red[256 + tid] += s_red[256 + tid + off];
                }
                __syncthreads();
            }
            float l0 = s_red[0] + ab[0], l1 = s_red[256] + ab[1];
            float a_r = 1.f / (1.f + expf(10.f * (l1 - l0)));
            float a_s = 1.f / (1.f + expf(10.f * (l0 - l1)));
            __syncthreads();
            // stack pop-scan
            float sval = (tid < Mm) ? scur[tid * Bb + e] : 0.f;
            s_scan[tid] = sval;
            __syncthreads();
            scan256(s_scan, tid);
            if (tid < Mm) {
                float P = s_scan[tid], Pm1 = tid ? s_scan[tid - 1] : 0.f;
                float w1 = fminf(P, a_r) - fminf(Pm1, a_r);
                float wt = fminf(P, 1.f + a_r) - fminf(Pm1, 1.f + a_r);
                s_w1[tid] = w1;
                s_w2[tid] = wt - w1;
                if (p == 0) {
                    float snv = sval - wt;
                    if (tid == idx)  snv = a_r;
                    if (tid == idx2) snv = a_s;
                    snxt[tid * Bb + e] = snv;
                }
            }
            __syncthreads();
            // r1, r2 dots (64 dims per block, 4-way m-split)
            int dl = tid & 63, ms = tid >> 6;
            int d = p * 64 + dl;
            int mstart = (ms == 0) ? 0 : (49 + 48 * (ms - 1));
            int mend = mstart + ((ms == 0) ? 49 : 48);
            float a1 = 0.f, a2 = 0.f;
            for (int m = mstart; m < mend; m++) {
                float v = V[((size_t)m * Bb + e) * Hh + d];
                a1 += s_w1[m] * v;
                a2 += s_w2[m] * v;
            }
            s_red[tid] = a1; s_red[256 + tid] = a2;
            __syncthreads();
            if (ms == 0) {
                float r1v = s_red[dl] + s_red[64 + dl] + s_red[128 + dl] + s_red[192 + dl];
                float r2v = s_red[256 + dl] + s_red[320 + dl] + s_red[384 + dl] + s_red[448 + dl];
                R1[e * Hh + d] = r1v;
                R2[e * Hh + d] = r2v;
            }
            __syncthreads();
            // buffer pop
            float sbval = (tid < Ss) ? sbcur[e * Ss + tid] : 0.f;
            s_scan[tid] = sbval;
            __syncthreads();
            scan256(s_scan, tid);
            if (tid < Ss) {
                float P = s_scan[tid], Pm1 = tid ? s_scan[tid - 1] : 0.f;
                float wbv = fminf(P, a_s) - fminf(Pm1, a_s);
                s_wb[tid] = wbv;
                if (p == 0) sbnxt[e * Ss + tid] = sbval - wbv;
            }
            __syncthreads();
            float acb = 0.f;
            for (int t2 = ms * 12; t2 < ms * 12 + 12; t2++)
                acb += s_wb[t2] * Bemb[(e * Ss + t2) * Hh + d];
            s_red[tid] = acb;
            __syncthreads();
            if (ms == 0) {
                float bv = s_red[dl] + s_red[64 + dl] + s_red[128 + dl] + s_red[192 + dl];
                V[((size_t)idx2 * Bb + e) * Hh + d] = bv;
            }
        }
        gbar(cnt, ++barnum * NBLK);

        // ---------- Phase T2: tree cell, V[idx] write, next xt ----------
        {
            int eg = bid >> 5, sl = bid & 31;
            int dbase = sl * 8;
            int el = tid >> 5, rr = tid & 31;
            int e = eg * 8 + el;
            // tree dots: 40 rows (8 dims x 5 gates) per 8 elements
            for (int pass = 0; pass < 2; pass++) {
                int g, dl;
                bool act;
                if (pass == 0) { g = rr >> 3; dl = rr & 7; act = true; }
                else           { g = 4;      dl = rr;     act = (rr < 8); }
                if (act) {
                    int row = g * Hh + dbase + dl;
                    float4 al = make_float4(0.f, 0.f, 0.f, 0.f);
                    float4 ar = make_float4(0.f, 0.f, 0.f, 0.f);
                    const float4* wl = reinterpret_cast<const float4*>(tlw + (size_t)row * Hh);
                    const float4* wr = reinterpret_cast<const float4*>(trw + (size_t)row * Hh);
                    const float4* p1 = reinterpret_cast<const float4*>(R1 + (size_t)e * Hh);
                    const float4* p2 = reinterpret_cast<const float4*>(R2 + (size_t)e * Hh);
                    #pragma unroll 4
                    for (int k = 0; k < Hh / 4; k++) {
                        float4 a = wl[k], b = p1[k];
                        al.x += a.x * b.x; al.y += a.y * b.y; al.z += a.z * b.z; al.w += a.w * b.w;
                        float4 c2 = wr[k], d2 = p2[k];
                        ar.x += c2.x * d2.x; ar.y += c2.y * d2.y; ar.z += c2.z * d2.z; ar.w += c2.w * d2.w;
                    }
                    s_tg[(el * 5 + g) * 8 + dl] =
                        tlb[row] + trb[row] + al.x + al.y + al.z + al.w + ar.x + ar.y + ar.z + ar.w;
                }
            }
            __syncthreads();
            if (tid < 64) {
                int el2 = tid >> 3, dl = tid & 7;
                int e2 = eg * 8 + el2, d = dbase + dl;
                float ta  = s_tg[(el2 * 5 + 0) * 8 + dl];
                float ti  = s_tg[(el2 * 5 + 1) * 8 + dl];
                float tf1 = s_tg[(el2 * 5 + 2) * 8 + dl];
                float tf2 = s_tg[(el2 * 5 + 3) * 8 + dl];
                float to  = s_tg[(el2 * 5 + 4) * 8 + dl];
                float rv1 = R1[e2 * Hh + d], rv2 = R2[e2 * Hh + d];
                float ct = tanhf(ta) * sigf(ti) + sigf(tf1) * rv1 + sigf(tf2) * rv2;
                float htv = sigf(to) * tanhf(ct);
                V[((size_t)idx * Bb + e2) * Hh + d] = htv;
                s_ht[tid] = htv;
            }
            __syncthreads();
            // 8-col stack scan over snxt (alpha = 1)
            for (int el2 = 0; el2 < 8; el2++)
                s_scan8[tid * 9 + el2] = (tid < Mm) ? snxt[tid * Bb + eg * 8 + el2] : 0.f;
            __syncthreads();
            for (int off = 1; off < 256; off <<= 1) {
                float pv[8];
                #pragma unroll
                for (int el2 = 0; el2 < 8; el2++)
                    pv[el2] = (tid >= off) ? s_scan8[(tid - off) * 9 + el2] : 0.f;
                __syncthreads();
                #pragma unroll
                for (int el2 = 0; el2 < 8; el2++)
                    s_scan8[tid * 9 + el2] += pv[el2];
                __syncthreads();
            }
            if (tid < Mm) {
                #pragma unroll
                for (int el2 = 0; el2 < 8; el2++) {
                    float P = s_scan8[tid * 9 + el2];
                    float Pm1 = tid ? s_scan8[(tid - 1) * 9 + el2] : 0.f;
                    float w1 = fminf(P, 1.f) - fminf(Pm1, 1.f);
                    float w2 = (fminf(P, 2.f) - fminf(Pm1, 2.f)) - w1;
                    s_w1e[el2 * 200 + tid] = w1;
                    s_w2e[el2 * 200 + tid] = w2;
                }
            }
            __syncthreads();
            // 8-col buffer scan over sbnxt (alpha = 1)
            for (int el2 = 0; el2 < 8; el2++)
                s_scan8[tid * 9 + el2] = (tid < Ss) ? sbnxt[(eg * 8 + el2) * Ss + tid] : 0.f;
            __syncthreads();
            for (int off = 1; off < 64; off <<= 1) {
                float pv[8];
                #pragma unroll
                for (int el2 = 0; el2 < 8; el2++)
                    pv[el2] = (tid >= off) ? s_scan8[(tid - off) * 9 + el2] : 0.f;
                __syncthreads();
                #pragma unroll
                for (int el2 = 0; el2 < 8; el2++)
                    s_scan8[tid * 9 + el2] += pv[el2];
                __syncthreads();
            }
            if (tid < Ss) {
                #pragma unroll
                for (int el2 = 0; el2 < 8; el2++) {
                    float P = s_scan8[tid * 9 + el2];
                    float Pm1 = tid ? s_scan8[(tid - 1) * 9 + el2] : 0.f;
                    s_wbe[el2 * 48 + tid] = fminf(P, 1.f) - fminf(Pm1, 1.f);
                }
            }
            __syncthreads();
            // next xt dots for block's (8e x 8d) tile
            int el3 = tid >> 5, dl3 = (tid >> 2) & 7, ms = tid & 3;
            int e3 = eg * 8 + el3, d3 = dbase + dl3;
            int mstart = (ms == 0) ? 0 : (49 + 48 * (ms - 1));
            int mend = mstart + ((ms == 0) ? 49 : 48);
            float a1 = 0.f, a2 = 0.f;
            for (int m = mstart; m < mend; m++) {
                float v = (m == idx) ? s_ht[el3 * 8 + dl3]
                                     : V[((size_t)m * Bb + e3) * Hh + d3];
                a1 += s_w1e[el3 * 200 + m] * v;
                a2 += s_w2e[el3 * 200 + m] * v;
            }
            float acb = 0.f;
            for (int t2 = ms * 12; t2 < ms * 12 + 12; t2++)
                acb += s_wbe[el3 * 48 + t2] * Bemb[(e3 * Ss + t2) * Hh + d3];
            s_red[tid] = a1; s_red[256 + tid] = a2; s_red[512 + tid] = acb;
            __syncthreads();
            if (ms == 0) {
                float x1v = s_red[tid] + s_red[tid + 1] + s_red[tid + 2] + s_red[tid + 3];
                float x2v = s_red[256 + tid] + s_red[257 + tid] + s_red[258 + tid] + s_red[259 + tid];
                float xbv = s_red[512 + tid] + s_red[513 + tid] + s_red[514 + tid] + s_red[515 + tid];
                XT[e3 * H3 + d3]       = xbv;
                XT[e3 * H3 + 256 + d3] = x1v;
                XT[e3 * H3 + 512 + d3] = x2v;
            }
        }
        gbar(cnt, ++barnum * NBLK);
    }

    // ================= MLP head =================
    {   // layer 0: relu(x1 @ l0_w^T + l0_b), input = XT[:, 256:512]
        int eg = bid >> 5, sl = bid & 31;
        int el = tid >> 5, r = tid & 31;
        int e = eg * 8 + el;
        int row = sl * 32 + r;
        float4 av = make_float4(0.f, 0.f, 0.f, 0.f);
        const float4* w4 = reinterpret_cast<const float4*>(l0w + (size_t)row * Hh);
        const float4* x4 = reinterpret_cast<const float4*>(XT + (size_t)e * H3 + 256);
        #pragma unroll 4
        for (int k = 0; k < Hh / 4; k++) {
            float4 a = w4[k], b = x4[k];
            av.x += a.x * b.x; av.y += a.y * b.y; av.z += a.z * b.z; av.w += a.w * b.w;
        }
        Y0[e * MLPD + row] = fmaxf(l0b[row] + av.x + av.y + av.z + av.w, 0.f);
    }
    gbar(cnt, ++barnum * NBLK);
    {   // layer 1
        int eg = bid >> 5, sl = bid & 31;
        int el = tid >> 5, r = tid & 31;
        int e = eg * 8 + el;
        int row = sl * 32 + r;
        float4 av = make_float4(0.f, 0.f, 0.f, 0.f);
        const float4* w4 = reinterpret_cast<const float4*>(l1w + (size_t)row * MLPD);
        const float4* x4 = reinterpret_cast<const float4*>(Y0 + (size_t)e * MLPD);
        #pragma unroll 4
        for (int k = 0; k < MLPD / 4; k++) {
            float4 a = w4[k], b = x4[k];
            av.x += a.x * b.x; av.y += a.y * b.y; av.z += a.z * b.z; av.w += a.w * b.w;
        }
        Y1[e * MLPD + row] = fmaxf(l1b[row] + av.x + av.y + av.z + av.w, 0.f);
    }
    gbar(cnt, ++barnum * NBLK);
    {   // layer 2: (64,3) output
        if (bid == 0 && tid < Bb * 3) {
            int e = tid / 3, r = tid % 3;
            float acc = l2b[r];
            const float* w = l2w + (size_t)r * MLPD;
            const float* yv = Y1 + (size_t)e * MLPD;
            for (int k = 0; k < MLPD; k++) acc += w[k] * yv[k];
            out[e * 3 + r] = acc;
        }
    }
}

extern "C" void kernel_launch(void* const* d_in, const int* in_sizes, int n_in,
                              void* d_out, int out_size, void* d_ws, size_t ws_size,
                              hipStream_t stream) {
    (void)in_sizes; (void)n_in; (void)out_size; (void)ws_size;
    // zero barrier counters (ws is re-poisoned 0xAA before every timed launch)
    (void)hipMemsetAsync(d_ws, 0, 256, stream);

    const int*   x_   = (const int*)d_in[0];
    const float* emb  = (const float*)d_in[1];
    const float* wih  = (const float*)d_in[2];
    const float* whh  = (const float*)d_in[3];
    const float* bih  = (const float*)d_in[4];
    const float* bhh  = (const float*)d_in[5];
    const float* aw   = (const float*)d_in[6];
    const float* ab   = (const float*)d_in[7];
    const float* tlw  = (const float*)d_in[8];
    const float* tlb  = (const float*)d_in[9];
    const float* trw  = (const float*)d_in[10];
    const float* trb  = (const float*)d_in[11];
    const float* l0w  = (const float*)d_in[12];
    const float* l0b  = (const float*)d_in[13];
    const float* l1w  = (const float*)d_in[14];
    const float* l1b  = (const float*)d_in[15];
    const float* l2w  = (const float*)d_in[16];
    const float* l2b  = (const float*)d_in[17];

    float* wsf = (float*)((char*)d_ws + 256);
    unsigned* bar = (unsigned*)d_ws;

    spinn_kernel<<<dim3(NBLK), dim3(NTHR), 0, stream>>>(
        x_, emb, wih, whh, bih, bhh, aw, ab, tlw, tlb, trw, trb,
        l0w, l0b, l1w, l1b, l2w, l2b, (float*)d_out, wsf, bar);
}

// Round 4
// 7021.551 us; speedup vs baseline: 2.1722x; 2.1722x over previous
//
#include <hip/hip_runtime.h>
#include <math.h>

#define NBLK 256
#define NTHR 256

typedef float vf4 __attribute__((ext_vector_type(4)));

namespace spinn {

constexpr int Bb = 64, Ss = 48, Hh = 256, TT = 96, Mm = 193, H3 = 768, MLPD = 1024;

__device__ __forceinline__ float sigf(float x) { return 1.0f / (1.0f + expf(-x)); }

#define FMA4(acc, a, b)                         \
    {                                           \
        acc.x = fmaf((a).x, (b).x, acc.x);      \
        acc.y = fmaf((a).y, (b).y, acc.y);      \
        acc.z = fmaf((a).z, (b).z, acc.z);      \
        acc.w = fmaf((a).w, (b).w, acc.w);      \
    }

// ---- coherent (device-scope, L1/L2-bypassing) access helpers ----
// Inline asm avoids both the gfx950 flat-atomic backend bug and volatile's
// per-op serialization. sc0 sc1 = read/write at the device coherence point,
// so per-XCD L2s keep read-only weights hot (we never emit cache
// invalidates anywhere in this kernel).
__device__ __forceinline__ void st_co(float* p, float v) {
    asm volatile("global_store_dword %0, %1, off sc0 sc1" :: "v"(p), "v"(v) : "memory");
}
__device__ __forceinline__ void ld_co_v4_1(const vf4* p0, vf4& r0) {
    asm volatile("global_load_dwordx4 %0, %1, off sc0 sc1\n\t"
                 "s_waitcnt vmcnt(0)"
                 : "=&v"(r0) : "v"(p0) : "memory");
}
__device__ __forceinline__ void ld_co_v4_2(const vf4* p0, const vf4* p1, vf4& r0, vf4& r1) {
    asm volatile("global_load_dwordx4 %0, %2, off sc0 sc1\n\t"
                 "global_load_dwordx4 %1, %3, off sc0 sc1\n\t"
                 "s_waitcnt vmcnt(0)"
                 : "=&v"(r0), "=&v"(r1) : "v"(p0), "v"(p1) : "memory");
}
__device__ __forceinline__ void ld_co_v4_3(const vf4* p0, const vf4* p1, const vf4* p2,
                                           vf4& r0, vf4& r1, vf4& r2) {
    asm volatile("global_load_dwordx4 %0, %3, off sc0 sc1\n\t"
                 "global_load_dwordx4 %1, %4, off sc0 sc1\n\t"
                 "global_load_dwordx4 %2, %5, off sc0 sc1\n\t"
                 "s_waitcnt vmcnt(0)"
                 : "=&v"(r0), "=&v"(r1), "=&v"(r2) : "v"(p0), "v"(p1), "v"(p2) : "memory");
}
__device__ __forceinline__ void ld_co_v4_4(const vf4* p0, const vf4* p1, const vf4* p2, const vf4* p3,
                                           vf4& r0, vf4& r1, vf4& r2, vf4& r3) {
    asm volatile("global_load_dwordx4 %0, %4, off sc0 sc1\n\t"
                 "global_load_dwordx4 %1, %5, off sc0 sc1\n\t"
                 "global_load_dwordx4 %2, %6, off sc0 sc1\n\t"
                 "global_load_dwordx4 %3, %7, off sc0 sc1\n\t"
                 "s_waitcnt vmcnt(0)"
                 : "=&v"(r0), "=&v"(r1), "=&v"(r2), "=&v"(r3)
                 : "v"(p0), "v"(p1), "v"(p2), "v"(p3) : "memory");
}
__device__ __forceinline__ void ld_co_f1x4(const float* p0, const float* p1, const float* p2,
                                           const float* p3, float& r0, float& r1, float& r2, float& r3) {
    asm volatile("global_load_dword %0, %4, off sc0 sc1\n\t"
                 "global_load_dword %1, %5, off sc0 sc1\n\t"
                 "global_load_dword %2, %6, off sc0 sc1\n\t"
                 "global_load_dword %3, %7, off sc0 sc1\n\t"
                 "s_waitcnt vmcnt(0)"
                 : "=&v"(r0), "=&v"(r1), "=&v"(r2), "=&v"(r3)
                 : "v"(p0), "v"(p1), "v"(p2), "v"(p3) : "memory");
}
__device__ __forceinline__ unsigned ld_co_u32(const unsigned* p) {
    unsigned r;
    asm volatile("global_load_dword %0, %1, off sc0 sc1\n\t"
                 "s_waitcnt vmcnt(0)"
                 : "=&v"(r) : "v"(p) : "memory");
    return r;
}

// ---- per-group (16-block) barrier ----
// Arrival: one fire-and-forget global_atomic_add. Spin: plain coherent
// LOADS (no RMW serialization). Release ordering: every wave drains its
// own write-through stores (vmcnt 0) before s_barrier; arrival follows.
__device__ __forceinline__ void gbar(unsigned* cnt, unsigned tgt) {
    asm volatile("s_waitcnt vmcnt(0)" ::: "memory");
    __syncthreads();
    if (threadIdx.x == 0) {
        unsigned one = 1u;
        asm volatile("global_atomic_add %0, %1, off" :: "v"(cnt), "v"(one) : "memory");
        while (ld_co_u32(cnt) < tgt) __builtin_amdgcn_s_sleep(1);
    }
    __syncthreads();
}

// ---- wave-level (64-lane) primitives ----
__device__ __forceinline__ float wave_iscan(float v, int lane) {
    #pragma unroll
    for (int off = 1; off < 64; off <<= 1) {
        float u = __shfl_up(v, off, 64);
        if (lane >= off) v += u;
    }
    return v;
}
__device__ __forceinline__ float wred64(float v) {
    #pragma unroll
    for (int off = 1; off < 64; off <<= 1) v += __shfl_xor(v, off, 64);
    return v;
}
__device__ __forceinline__ float wred_ms(float v) {  // reduce over lane bits 4,5 (the 4 ms groups)
    v += __shfl_xor(v, 16, 64);
    v += __shfl_xor(v, 32, 64);
    return v;
}

}  // namespace spinn

using namespace spinn;

__global__ void __launch_bounds__(NTHR, 1) spinn_kernel(
    const int* __restrict__ x, const float* __restrict__ emb,
    const float* __restrict__ wih, const float* __restrict__ whh,
    const float* __restrict__ bih, const float* __restrict__ bhh,
    const float* __restrict__ aw, const float* __restrict__ ab,
    const float* __restrict__ tlw, const float* __restrict__ tlb,
    const float* __restrict__ trw, const float* __restrict__ trb,
    const float* __restrict__ l0w, const float* __restrict__ l0b,
    const float* __restrict__ l1w, const float* __restrict__ l1b,
    const float* __restrict__ l2w, const float* __restrict__ l2b,
    float* __restrict__ out, float* __restrict__ wsf, unsigned* __restrict__ bar)
{
    const int tid = threadIdx.x;
    const int bid = blockIdx.x;
    const int eg = bid >> 4;          // element group (4 elements)
    const int q  = bid & 15;          // dim slice (16 dims)
    const int e0 = eg * 4;
    const int db = q * 16;

    unsigned* cnt = bar + eg * 32;    // per-group counter, 128B apart
    unsigned barnum = 0;

    // ---- global workspace (floats) ----
    float* XTg  = wsf;                          // [64][768]
    float* Hbg  = XTg + 64 * H3;                // [64][256]
    float* R1g  = Hbg + 64 * Hh;                // [64][256]
    float* R2g  = R1g + 64 * Hh;                // [64][256]
    float* Y0g  = R2g + 64 * Hh;                // [64][1024]
    float* Y1g  = Y0g + 64 * MLPD;              // [64][1024]
    float* Vall = Y1g + 64 * MLPD;
    float* Ball = Vall + (size_t)NBLK * (Mm * 64);
    float* Vg   = Vall + (size_t)bid * (Mm * 64);   // private [193][4 el][16 d]
    float* Bg   = Ball + (size_t)bid * (4 * Ss * 16); // private [4 el][48][16 d]

    // ---- LDS ----
    __shared__ float s_big[4096];    // union: s_xt[4][768] | (s_r1[4][256]+s_r2[4][256]) | MLP staging
    __shared__ float s_h[1024];      // [4][256] h_{t} (loaded in T1, used next L)
    __shared__ float s_c[64];        // [4][16] private c
    __shared__ float s_g[256];       // [4][4 gates][16]
    __shared__ float s_tg[320];      // [4][5 gates][16]
    __shared__ float s_s[800];       // [4][200] stack strengths (replicated per block)
    __shared__ float s_sb[192];      // [4][48] buffer strengths
    __shared__ float sw1[800], sw2[800];   // scan-weight scratch (pop, then push)
    __shared__ float s_wb[192], s_wbe[192];
    __shared__ float s_wx[16];       // [4][4]: w1e[idx], w2e[idx], w1e[idx2], w2e[idx2]
    __shared__ float s_xp1[64], s_xp2[64], s_xpb[64]; // xt partials [4][16]

    float* s_xt = s_big;             // [4][768]
    float* s_r1 = s_big;             // [4][256]
    float* s_r2 = s_big + 1024;      // [4][256]

    const int lane = tid & 63;
    const int elw  = tid >> 6;       // wave id == element for per-wave work
    const int ms   = lane >> 4;
    const int dl   = lane & 15;

    // ================= INIT =================
    {
        // B embedding gather (private), buffer strengths, zero state
        for (int i = tid; i < 4 * Ss * 16; i += NTHR) {
            int el = i / (Ss * 16);
            int rem = i - el * (Ss * 16);
            int s = rem >> 4, d = rem & 15;
            int tok = x[(e0 + el) * Ss + s];
            Bg[i] = emb[(size_t)tok * Hh + db + d];
        }
        if (tid < 4 * Ss) {
            int el = tid / Ss, s = tid % Ss;
            s_sb[tid] = (x[(e0 + el) * Ss + s] > 0) ? 1.0f : 0.0f;
        }
        for (int i = tid; i < 800; i += NTHR) s_s[i] = 0.0f;
        for (int i = tid; i < 1024; i += NTHR) s_h[i] = 0.0f;
        if (tid < 64) s_c[tid] = 0.0f;
        for (int i = tid; i < Mm * 64; i += NTHR) Vg[i] = 0.0f;
        asm volatile("s_waitcnt vmcnt(0)" ::: "memory");
        __syncthreads();
        // initial x_b = read_buffer(ones); x1 = x2 = 0
        float sbv = (lane < Ss) ? s_sb[elw * Ss + lane] : 0.0f;
        float P = wave_iscan(sbv, lane);
        float wbe = fminf(P, 1.0f) - fminf(P - sbv, 1.0f);
        if (lane < Ss) s_wbe[elw * Ss + lane] = wbe;
        float axb = 0.0f;
        for (int t2 = ms * 12; t2 < ms * 12 + 12; t2++)
            axb = fmaf(s_wbe[elw * Ss + t2], Bg[elw * (Ss * 16) + t2 * 16 + dl], axb);
        axb = wred_ms(axb);
        if (lane < 16) {
            float* xte = XTg + (size_t)(e0 + elw) * H3;
            st_co(xte + db + dl, axb);
            st_co(xte + 256 + db + dl, 0.0f);
            st_co(xte + 512 + db + dl, 0.0f);
        }
    }
    gbar(cnt, ++barnum * 16);

    // ================= time loop =================
    for (int t = 0; t < TT; t++) {
        const int idx  = 191 - 2 * t;
        const int idx2 = idx - 1;

        // ---------- Phase L: LSTM ----------
        {
            // stage full xt for 4 elements (coherent)
            const vf4* src = (const vf4*)XTg + (size_t)e0 * 192;
            vf4 a, b, c;
            ld_co_v4_3(src + tid, src + tid + 256, src + tid + 512, a, b, c);
            vf4* sx4 = (vf4*)s_xt;
            sx4[tid] = a; sx4[tid + 256] = b; sx4[tid + 512] = c;
            __syncthreads();
            // gate dots: thread = (el, gate, dl)
            int r = tid & 63, g = r >> 4, d = r & 15;
            int row = g * Hh + db + d;
            const vf4* w4  = (const vf4*)wih + (size_t)row * 192;
            const vf4* x4  = (const vf4*)s_xt + elw * 192;
            const vf4* wh4 = (const vf4*)whh + (size_t)row * 64;
            const vf4* h4  = (const vf4*)s_h + elw * 64;
            vf4 acc4 = {0.f, 0.f, 0.f, 0.f};
            #pragma unroll 4
            for (int k = 0; k < 192; k++) { vf4 wv = w4[k], xv = x4[k]; FMA4(acc4, wv, xv); }
            #pragma unroll 4
            for (int k = 0; k < 64; k++)  { vf4 wv = wh4[k], hv = h4[k]; FMA4(acc4, wv, hv); }
            s_g[elw * 64 + g * 16 + d] = bih[row] + bhh[row] + acc4.x + acc4.y + acc4.z + acc4.w;
            __syncthreads();
            if (tid < 64) {
                int el2 = tid >> 4, d2 = tid & 15;
                float gi = s_g[el2 * 64 + d2], gf = s_g[el2 * 64 + 16 + d2];
                float gg = s_g[el2 * 64 + 32 + d2], go = s_g[el2 * 64 + 48 + d2];
                float cv = sigf(gf) * s_c[tid] + sigf(gi) * tanhf(gg);
                s_c[tid] = cv;
                float hv = sigf(go) * tanhf(cv);
                st_co(Hbg + (size_t)(e0 + el2) * Hh + db + d2, hv);
            }
        }
        gbar(cnt, ++barnum * 16);

        // ---------- Phase T1 (fully per-wave; wave = element) ----------
        {
            const int e = e0 + elw;
            // full h load (coherent) -> LDS for next L; alpha logits
            float h0, h1, h2, h3;
            const float* hb = Hbg + (size_t)e * Hh + lane;
            ld_co_f1x4(hb, hb + 64, hb + 128, hb + 192, h0, h1, h2, h3);
            s_h[elw * Hh + lane] = h0;       s_h[elw * Hh + 64 + lane] = h1;
            s_h[elw * Hh + 128 + lane] = h2; s_h[elw * Hh + 192 + lane] = h3;
            float lg0 = h0 * aw[lane] + h1 * aw[64 + lane] + h2 * aw[128 + lane] + h3 * aw[192 + lane];
            float lg1 = h0 * aw[256 + lane] + h1 * aw[320 + lane] + h2 * aw[384 + lane] + h3 * aw[448 + lane];
            lg0 = wred64(lg0) + ab[0];
            lg1 = wred64(lg1) + ab[1];
            float a_r = 1.0f / (1.0f + expf(10.0f * (lg1 - lg0)));
            float a_s = 1.0f / (1.0f + expf(10.0f * (lg0 - lg1)));
            // pop scan over s (4 m per lane)
            int m0 = lane * 4;
            float v0 = (m0     < Mm) ? s_s[elw * 200 + m0]     : 0.0f;
            float v1 = (m0 + 1 < Mm) ? s_s[elw * 200 + m0 + 1] : 0.0f;
            float v2 = (m0 + 2 < Mm) ? s_s[elw * 200 + m0 + 2] : 0.0f;
            float v3 = (m0 + 3 < Mm) ? s_s[elw * 200 + m0 + 3] : 0.0f;
            float c1 = v0 + v1, c2 = c1 + v2, c3 = c2 + v3;
            float inc = c3;
            #pragma unroll
            for (int off = 1; off < 64; off <<= 1) {
                float u = __shfl_up(inc, off, 64);
                if (lane >= off) inc += u;
            }
            float ex = inc - c3;
            float Pv[4]  = {ex + v0, ex + c1, ex + c2, ex + c3};
            float Pp[4]  = {ex, ex + v0, ex + c1, ex + c2};
            float vv_[4] = {v0, v1, v2, v3};
            float sn[4];
            #pragma unroll
            for (int i = 0; i < 4; i++) {
                int m = m0 + i;
                float w1 = fminf(Pv[i], a_r) - fminf(Pp[i], a_r);
                float wt = fminf(Pv[i], 1.0f + a_r) - fminf(Pp[i], 1.0f + a_r);
                float s2 = vv_[i] - wt;
                if (m == idx) s2 = a_r;
                if (m == idx2) s2 = a_s;
                sn[i] = s2;
                if (m < Mm) {
                    sw1[elw * 200 + m] = w1;
                    sw2[elw * 200 + m] = wt - w1;
                    s_s[elw * 200 + m] = s2;
                }
            }
            // r1/r2 dots (lane = ms*16+dl, m-split by ms)
            int mA = ms * 48, mB = (ms == 3) ? Mm : (mA + 48);
            float a1 = 0.0f, a2 = 0.0f;
            for (int m = mA; m < mB; m++) {
                float vv = Vg[m * 64 + elw * 16 + dl];
                a1 = fmaf(sw1[elw * 200 + m], vv, a1);
                a2 = fmaf(sw2[elw * 200 + m], vv, a2);
            }
            a1 = wred_ms(a1); a2 = wred_ms(a2);
            if (lane < 16) {
                st_co(R1g + (size_t)e * Hh + db + dl, a1);
                st_co(R2g + (size_t)e * Hh + db + dl, a2);
            }
            // push scan (alpha = 1) on updated s (values in sn registers)
            float d1 = sn[0] + sn[1], d2 = d1 + sn[2], d3 = d2 + sn[3];
            float inc2 = d3;
            #pragma unroll
            for (int off = 1; off < 64; off <<= 1) {
                float u = __shfl_up(inc2, off, 64);
                if (lane >= off) inc2 += u;
            }
            float ex2 = inc2 - d3;
            float Qv[4] = {ex2 + sn[0], ex2 + d1, ex2 + d2, ex2 + d3};
            float Qp[4] = {ex2, ex2 + sn[0], ex2 + d1, ex2 + d2};
            #pragma unroll
            for (int i = 0; i < 4; i++) {
                int m = m0 + i;
                float w1e = fminf(Qv[i], 1.0f) - fminf(Qp[i], 1.0f);
                float w2e = (fminf(Qv[i], 2.0f) - fminf(Qp[i], 2.0f)) - w1e;
                if (m == idx)  { s_wx[elw * 4 + 0] = w1e; s_wx[elw * 4 + 1] = w2e; w1e = 0.0f; w2e = 0.0f; }
                if (m == idx2) { s_wx[elw * 4 + 2] = w1e; s_wx[elw * 4 + 3] = w2e; w1e = 0.0f; w2e = 0.0f; }
                if (m < Mm) { sw1[elw * 200 + m] = w1e; sw2[elw * 200 + m] = w2e; }
            }
            // buffer pop + push scans
            float sbv = (lane < Ss) ? s_sb[elw * Ss + lane] : 0.0f;
            float Pb = wave_iscan(sbv, lane);
            float wb = fminf(Pb, a_s) - fminf(Pb - sbv, a_s);
            float sbn = sbv - wb;
            float Pb2 = wave_iscan(sbn, lane);
            float wbe = fminf(Pb2, 1.0f) - fminf(Pb2 - sbn, 1.0f);
            if (lane < Ss) {
                s_sb[elw * Ss + lane] = sbn;
                s_wb[elw * Ss + lane] = wb;
                s_wbe[elw * Ss + lane] = wbe;
            }
            // buf (V[idx2]) and xb dots
            float abf = 0.0f, axb = 0.0f;
            for (int t2 = ms * 12; t2 < ms * 12 + 12; t2++) {
                float be = Bg[elw * (Ss * 16) + t2 * 16 + dl];
                abf = fmaf(s_wb[elw * Ss + t2], be, abf);
                axb = fmaf(s_wbe[elw * Ss + t2], be, axb);
            }
            abf = wred_ms(abf); axb = wred_ms(axb);
            if (lane < 16) Vg[idx2 * 64 + elw * 16 + dl] = abf;  // private store
            // x1/x2 partial dots (idx & idx2 weights zeroed; idx2 term via register)
            float x1 = 0.0f, x2 = 0.0f;
            for (int m = mA; m < mB; m++) {
                float vv = Vg[m * 64 + elw * 16 + dl];
                x1 = fmaf(sw1[elw * 200 + m], vv, x1);
                x2 = fmaf(sw2[elw * 200 + m], vv, x2);
            }
            if (ms == 0) {
                x1 = fmaf(s_wx[elw * 4 + 2], abf, x1);
                x2 = fmaf(s_wx[elw * 4 + 3], abf, x2);
            }
            x1 = wred_ms(x1); x2 = wred_ms(x2);
            if (lane < 16) {
                s_xp1[elw * 16 + dl] = x1;
                s_xp2[elw * 16 + dl] = x2;
                s_xpb[elw * 16 + dl] = axb;
            }
        }
        gbar(cnt, ++barnum * 16);

        // ---------- Phase T2: tree cell + finish xt ----------
        {
            const vf4* pR1 = (const vf4*)R1g + (size_t)e0 * 64 + tid;
            const vf4* pR2 = (const vf4*)R2g + (size_t)e0 * 64 + tid;
            vf4 ra, rb;
            ld_co_v4_2(pR1, pR2, ra, rb);
            ((vf4*)s_r1)[tid] = ra;
            ((vf4*)s_r2)[tid] = rb;
            __syncthreads();
            // tree dots, pass1: 4 gates x 16 dims x 4 el
            {
                int r = tid & 63, g = r >> 4, d = r & 15;
                int row = g * Hh + db + d;
                const vf4* wl = (const vf4*)tlw + (size_t)row * 64;
                const vf4* wr = (const vf4*)trw + (size_t)row * 64;
                const vf4* p1 = (const vf4*)s_r1 + elw * 64;
                const vf4* p2 = (const vf4*)s_r2 + elw * 64;
                vf4 acc4 = {0.f, 0.f, 0.f, 0.f};
                #pragma unroll 4
                for (int k = 0; k < 64; k++) {
                    vf4 w1v = wl[k], r1v = p1[k]; FMA4(acc4, w1v, r1v);
                    vf4 w2v = wr[k], r2v = p2[k]; FMA4(acc4, w2v, r2v);
                }
                s_tg[elw * 80 + g * 16 + d] =
                    tlb[row] + trb[row] + acc4.x + acc4.y + acc4.z + acc4.w;
            }
            // pass2: gate 4 (output gate)
            if (tid < 64) {
                int el2 = tid >> 4, d2 = tid & 15;
                int row = 4 * Hh + db + d2;
                const vf4* wl = (const vf4*)tlw + (size_t)row * 64;
                const vf4* wr = (const vf4*)trw + (size_t)row * 64;
                const vf4* p1 = (const vf4*)s_r1 + el2 * 64;
                const vf4* p2 = (const vf4*)s_r2 + el2 * 64;
                vf4 acc4 = {0.f, 0.f, 0.f, 0.f};
                #pragma unroll 4
                for (int k = 0; k < 64; k++) {
                    vf4 w1v = wl[k], r1v = p1[k]; FMA4(acc4, w1v, r1v);
                    vf4 w2v = wr[k], r2v = p2[k]; FMA4(acc4, w2v, r2v);
                }
                s_tg[el2 * 80 + 64 + d2] =
                    tlb[row] + trb[row] + acc4.x + acc4.y + acc4.z + acc4.w;
            }
            __syncthreads();
            if (tid < 64) {
                int el2 = tid >> 4, d2 = tid & 15;
                int e = e0 + el2;
                float ta  = s_tg[el2 * 80 + d2];
                float ti  = s_tg[el2 * 80 + 16 + d2];
                float tf1 = s_tg[el2 * 80 + 32 + d2];
                float tf2 = s_tg[el2 * 80 + 48 + d2];
                float to  = s_tg[el2 * 80 + 64 + d2];
                float r1d = s_r1[el2 * Hh + db + d2];
                float r2d = s_r2[el2 * Hh + db + d2];
                float ct = tanhf(ta) * sigf(ti) + sigf(tf1) * r1d + sigf(tf2) * r2d;
                float ht = sigf(to) * tanhf(ct);
                Vg[idx * 64 + el2 * 16 + d2] = ht;  // private store
                float x1f = fmaf(s_wx[el2 * 4 + 0], ht, s_xp1[tid]);
                float x2f = fmaf(s_wx[el2 * 4 + 1], ht, s_xp2[tid]);
                float* xte = XTg + (size_t)e * H3;
                st_co(xte + db + d2, s_xpb[tid]);
                st_co(xte + 256 + db + d2, x1f);
                st_co(xte + 512 + db + d2, x2f);
            }
        }
        gbar(cnt, ++barnum * 16);
    }

    // ================= MLP head =================
    {   // layer 0: input = XT[:, 256:512]
        int j = tid & 63;
        const vf4* px = (const vf4*)XTg + (size_t)(e0 + elw) * 192 + 64 + j;
        vf4 xv;
        ld_co_v4_1(px, xv);
        ((vf4*)s_r1)[elw * 64 + j] = xv;
        __syncthreads();
        int row = q * 64 + (tid & 63);
        const vf4* w = (const vf4*)l0w + (size_t)row * 64;
        const vf4* xx = (const vf4*)s_r1 + elw * 64;
        vf4 acc4 = {0.f, 0.f, 0.f, 0.f};
        #pragma unroll 4
        for (int k = 0; k < 64; k++) { vf4 wv = w[k], v = xx[k]; FMA4(acc4, wv, v); }
        float y = fmaxf(l0b[row] + acc4.x + acc4.y + acc4.z + acc4.w, 0.0f);
        st_co(Y0g + (size_t)(e0 + elw) * MLPD + row, y);
    }
    gbar(cnt, ++barnum * 16);
    {   // layer 1
        const vf4* p = (const vf4*)Y0g + (size_t)e0 * 256;
        vf4 y0, y1, y2, y3;
        ld_co_v4_4(p + tid, p + tid + 256, p + tid + 512, p + tid + 768, y0, y1, y2, y3);
        vf4* sy = (vf4*)s_big;
        sy[tid] = y0; sy[tid + 256] = y1; sy[tid + 512] = y2; sy[tid + 768] = y3;
        __syncthreads();
        int row = q * 64 + (tid & 63);
        const vf4* w = (const vf4*)l1w + (size_t)row * 256;
        const vf4* yy = sy + elw * 256;
        vf4 acc4 = {0.f, 0.f, 0.f, 0.f};
        #pragma unroll 4
        for (int k = 0; k < 256; k++) { vf4 wv = w[k], v = yy[k]; FMA4(acc4, wv, v); }
        float y = fmaxf(l1b[row] + acc4.x + acc4.y + acc4.z + acc4.w, 0.0f);
        st_co(Y1g + (size_t)(e0 + elw) * MLPD + row, y);
    }
    gbar(cnt, ++barnum * 16);
    if (q < 4) {  // layer 2: block (eg, q=el) handles element e0+q
        int e = e0 + q;
        const vf4* p = (const vf4*)Y1g + (size_t)e * 256 + tid;
        vf4 yv;
        ld_co_v4_1(p, yv);
        #pragma unroll
        for (int r = 0; r < 3; r++) {
            const float* w = l2w + (size_t)r * MLPD + tid * 4;
            s_h[r * 256 + tid] = yv.x * w[0] + yv.y * w[1] + yv.z * w[2] + yv.w * w[3];
        }
        __syncthreads();
        for (int off = 128; off >= 1; off >>= 1) {
            if (tid < off) {
                #pragma unroll
                for (int r = 0; r < 3; r++)
                    s_h[r * 256 + tid] += s_h[r * 256 + tid + off];
            }
            __syncthreads();
        }
        if (tid < 3) out[e * 3 + tid] = s_h[tid * 256] + l2b[tid];
    }
}

extern "C" void kernel_launch(void* const* d_in, const int* in_sizes, int n_in,
                              void* d_out, int out_size, void* d_ws, size_t ws_size,
                              hipStream_t stream) {
    (void)in_sizes; (void)n_in; (void)out_size; (void)ws_size;
    (void)hipMemsetAsync(d_ws, 0, 4096, stream);  // per-group barrier counters

    const int*   x_   = (const int*)d_in[0];
    const float* emb  = (const float*)d_in[1];
    const float* wih  = (const float*)d_in[2];
    const float* whh  = (const float*)d_in[3];
    const float* bih  = (const float*)d_in[4];
    const float* bhh  = (const float*)d_in[5];
    const float* aw   = (const float*)d_in[6];
    const float* ab   = (const float*)d_in[7];
    const float* tlw  = (const float*)d_in[8];
    const float* tlb  = (const float*)d_in[9];
    const float* trw  = (const float*)d_in[10];
    const float* trb  = (const float*)d_in[11];
    const float* l0w  = (const float*)d_in[12];
    const float* l0b  = (const float*)d_in[13];
    const float* l1w  = (const float*)d_in[14];
    const float* l1b  = (const float*)d_in[15];
    const float* l2w  = (const float*)d_in[16];
    const float* l2b  = (const float*)d_in[17];

    float* wsf = (float*)((char*)d_ws + 4096);
    unsigned* bar = (unsigned*)d_ws;

    spinn_kernel<<<dim3(NBLK), dim3(NTHR), 0, stream>>>(
        x_, emb, wih, whh, bih, bhh, aw, ab, tlw, tlb, trw, trb,
        l0w, l0b, l1w, l1b, l2w, l2b, (float*)d_out, wsf, bar);
}